// Round 19
// baseline (386.083 us; speedup 1.0000x reference)
//
#include <hip/hip_runtime.h>
#include <hip/hip_bf16.h>

// ---------------------------------------------------------------------------
// S4D stack, MFMA everywhere, single in-place state buffer u (bf16 [H][M]):
// prep: cvt(Wo+enc_W, 1 launch); mats_all (params inline, all layers).
// encoder MFMA (f32 x inline cvt -> u cm) -> 4x[ fused SSM; GLU MFMA + LN v13
//   (512 thr, 2 tiles parallel, single-buffer A->R restage; u in-place) ]
// -> decoder (pair-interleaved staging).
// glu LDS rows: dword[pos][130]: dword p of row pos = short2(ch 2p, ch 2p+1)
// ---------------------------------------------------------------------------

constexpr int B_ = 4, L_ = 8192, DIN = 64, H_ = 256, N2_ = 32, NL_ = 4, DOUT = 10;
constexpr int LC = 64, CHK = L_ / LC;     // 128 chunks/batch
constexpr int M_ = B_ * L_;               // 32768 positions

// ws layout in float slots
constexpr size_t OFF_EWB  = 1048576;                   // bf16 enc_W [256*64]
constexpr size_t OFF_WOB  = 8388608;                   // bf16 Wo NL*512*256
constexpr size_t OFF_PWLC = 8781824;                   // f32 w^64 pairs (mats_all -> ssm)
constexpr size_t OFF_UCM  = 8929280;                   // bf16 [H][M] u (in-place)
constexpr size_t OFF_YCM  = 13123584;                  // bf16 [H][M] y cm
constexpr size_t OFF_MTA  = 17317888;                  // bf16 Ttr [NL][H][64][64]
constexpr size_t OFF_MWA  = 19415040;                  // bf16 Wtr [NL][H][64][64]
constexpr size_t OFF_MVA  = 21512192;                  // bf16 Vtr [NL][H][64][64]
// end 23609344 slots = 94.4 MB

typedef short bf16x8 __attribute__((ext_vector_type(8)));
typedef short short8 __attribute__((ext_vector_type(8)));
typedef short short4v __attribute__((ext_vector_type(4)));
typedef float f32x4  __attribute__((ext_vector_type(4)));
typedef int   int2v  __attribute__((ext_vector_type(2)));

__device__ __forceinline__ float b2f(short s) {
    union { float f; unsigned u; } c;
    c.u = ((unsigned)(unsigned short)s) << 16;
    return c.f;
}

// ---------------------------------------------------------------------------
// fused convert: Wo (n4a float4s) then enc_W (n4b float4s), one launch
__global__ __launch_bounds__(256) void k_wcvt2(const float* __restrict__ a,
    __hip_bfloat16* __restrict__ da, int n4a, const float* __restrict__ b,
    __hip_bfloat16* __restrict__ db, int n4b)
{
    int i = blockIdx.x * 256 + threadIdx.x;
    const float* s; __hip_bfloat16* d; int j;
    if (i < n4a) { s = a; d = da; j = i; }
    else if (i < n4a + n4b) { s = b; d = db; j = i - n4a; }
    else return;
    float4 v = ((const float4*)s)[j];
    union { __hip_bfloat16 bb[4]; uint2 u; } o;
    o.bb[0] = __float2bfloat16(v.x); o.bb[1] = __float2bfloat16(v.y);
    o.bb[2] = __float2bfloat16(v.z); o.bb[3] = __float2bfloat16(v.w);
    ((uint2*)d)[j] = o.u;
}

// ---------------------------------------------------------------------------
// ALL-LAYER mats with inline param computation; also writes PWLC for ssm.
__global__ __launch_bounds__(256) void k_mats_all(
    const float* __restrict__ log_dt, const float* __restrict__ log_A_re,
    const float* __restrict__ A_im, const float* __restrict__ C_re,
    const float* __restrict__ C_im, float* __restrict__ ws,
    __hip_bfloat16* __restrict__ mt, __hip_bfloat16* __restrict__ mw,
    __hip_bfloat16* __restrict__ mv)
{
    int bid = blockIdx.x;                  // NL*H blocks
    int lh = bid;
    int tid = threadIdx.x;
    __shared__ float zre[32], zim[32], ctr[32], cti[32], kv[64];
    if (tid < 32) {
        int idx = lh * N2_ + tid;
        float dt  = expf(log_dt[lh]);
        float Are = -expf(log_A_re[idx]);
        float Aim = A_im[idx];
        float zr = dt * Are, zi = dt * Aim;
        float er = expf(zr);
        float wre = er * cosf(zi), wim = er * sinf(zi);
        float d = Are * Are + Aim * Aim;
        float nre = wre - 1.f, nim = wim;
        float qre = (nre * Are + nim * Aim) / d;
        float qim = (nim * Are - nre * Aim) / d;
        float cr = C_re[idx], ci = C_im[idx];
        zre[tid] = zr; zim[tid] = zi;
        ctr[tid] = 2.f * (cr * qre - ci * qim);
        cti[tid] = 2.f * (cr * qim + ci * qre);
        float er2 = expf(zr * (float)LC);
        ((float2*)(ws + OFF_PWLC))[idx] =
            make_float2(er2 * cosf(zi * (float)LC), er2 * sinf(zi * (float)LC));
    }
    __syncthreads();
    if (tid < 64) {
        float d = (float)tid, acc = 0.f;
        for (int n = 0; n < 32; n++) {
            float er = expf(zre[n] * d);
            float co = cosf(zim[n] * d), si = sinf(zim[n] * d);
            acc += er * (ctr[n] * co - cti[n] * si);
        }
        kv[tid] = acc;
    }
    __syncthreads();
    {   // Ttr
        int t = tid >> 2, j0 = (tid & 3) * 16;
        alignas(16) __hip_bfloat16 row[16];
        #pragma unroll
        for (int jj = 0; jj < 16; jj++) {
            int j = j0 + jj;
            row[jj] = __float2bfloat16(j <= t ? kv[t - j] : 0.f);
        }
        *(short8*)(mt + (size_t)lh*4096 + t*64 + j0)     = *(short8*)&row[0];
        *(short8*)(mt + (size_t)lh*4096 + t*64 + j0 + 8) = *(short8*)&row[8];
    }
    {   // Wtr
        int n = tid >> 3, j0 = (tid & 7) * 8;
        alignas(16) __hip_bfloat16 rre[8], rim[8];
        #pragma unroll
        for (int jj = 0; jj < 8; jj++) {
            float e = (float)(63 - (j0 + jj));
            float er = expf(zre[n] * e);
            rre[jj] = __float2bfloat16(er * cosf(zim[n] * e));
            rim[jj] = __float2bfloat16(er * sinf(zim[n] * e));
        }
        *(short8*)(mw + (size_t)lh*4096 + (2*n)*64 + j0)   = *(short8*)&rre[0];
        *(short8*)(mw + (size_t)lh*4096 + (2*n+1)*64 + j0) = *(short8*)&rim[0];
    }
    {   // Vtr
        int t = tid >> 2, n0 = (tid & 3) * 8;
        float e = (float)(t + 1);
        alignas(16) __hip_bfloat16 row[16];
        #pragma unroll
        for (int k = 0; k < 8; k++) {
            int n = n0 + k;
            float er = expf(zre[n] * e);
            float wr = er * cosf(zim[n] * e), wi = er * sinf(zim[n] * e);
            row[2*k]   = __float2bfloat16(ctr[n]*wr - cti[n]*wi);
            row[2*k+1] = __float2bfloat16(-(ctr[n]*wi + cti[n]*wr));
        }
        *(short8*)(mv + (size_t)lh*4096 + t*64 + 2*n0)     = *(short8*)&row[0];
        *(short8*)(mv + (size_t)lh*4096 + t*64 + 2*n0 + 8) = *(short8*)&row[8];
    }
}

// ---------------------------------------------------------------------------
// encoder MFMA: u[cm] = (x @ ewb^T + b); x f32 converted inline via LDS
__global__ __launch_bounds__(256) void k_encoder(const float* __restrict__ x,
    const __hip_bfloat16* __restrict__ ewb, const float* __restrict__ enc_b,
    __hip_bfloat16* __restrict__ u)
{
    __shared__ short sbuf[256 * 66];        // xls [64][72] alias; lt
    short* xls = sbuf;
    int tid = threadIdx.x;
    int w = tid >> 6, l = tid & 63, l15 = l & 15, l4 = l >> 4;
    int m0 = blockIdx.x * 64;
    int nv = w * 64;
    {   // stage x f32 -> bf16 LDS [row][72]
        const float4* x4 = (const float4*)x;
        #pragma unroll
        for (int q = 0; q < 4; q++) {
            int f = tid * 4 + q;
            float4 v = x4[(size_t)m0 * 16 + f];
            int e = f * 4, row = e >> 6, col = e & 63;
            alignas(8) __hip_bfloat16 t4[4] = {
                __float2bfloat16(v.x), __float2bfloat16(v.y),
                __float2bfloat16(v.z), __float2bfloat16(v.w) };
            *(short4v*)&xls[row * 72 + col] = *(short4v*)t4;
        }
    }
    __syncthreads();
    f32x4 acc[4][4];
    #pragma unroll
    for (int mi = 0; mi < 4; mi++)
        #pragma unroll
        for (int nj = 0; nj < 4; nj++) acc[mi][nj] = (f32x4)0.f;
    #pragma unroll
    for (int ks = 0; ks < 2; ks++) {
        int k0 = ks * 32 + l4 * 8;
        bf16x8 a[4];
        #pragma unroll
        for (int mi = 0; mi < 4; mi++)
            a[mi] = *(const bf16x8*)&xls[(mi * 16 + l15) * 72 + k0];
        #pragma unroll
        for (int nj = 0; nj < 4; nj++) {
            bf16x8 b = *(const bf16x8*)(ewb + (size_t)(nv + nj * 16 + l15) * 64 + k0);
            #pragma unroll
            for (int mi = 0; mi < 4; mi++)
                acc[mi][nj] = __builtin_amdgcn_mfma_f32_16x16x32_bf16(a[mi], b, acc[mi][nj], 0, 0, 0);
        }
    }
    float bov[4];
    #pragma unroll
    for (int nj = 0; nj < 4; nj++) bov[nj] = enc_b[nv + nj * 16 + l15];
    __syncthreads();                        // xls dead -> lt
    #pragma unroll
    for (int mi = 0; mi < 4; mi++)
        #pragma unroll
        for (int r = 0; r < 4; r++) {
            int lr = mi * 16 + l4 * 4 + r;
            #pragma unroll
            for (int nj = 0; nj < 4; nj++) {
                int cn = nv + nj * 16 + l15;
                __hip_bfloat16 bv = __float2bfloat16(acc[mi][nj][r] + bov[nj]);
                sbuf[cn * 66 + lr] = *(short*)&bv;
            }
        }
    __syncthreads();
    #pragma unroll
    for (int q = 0; q < 8; q++)
        *(short8*)(u + (size_t)tid * M_ + m0 + q * 8) = *(short8*)&sbuf[tid * 66 + q * 8];
}

// ---------------------------------------------------------------------------
// FUSED SSM (unchanged)
__global__ __launch_bounds__(256) void k_ssm(const __hip_bfloat16* __restrict__ ucm,
    const __hip_bfloat16* __restrict__ mt, const __hip_bfloat16* __restrict__ mw,
    const __hip_bfloat16* __restrict__ mv, const float* __restrict__ ws, int layer,
    const float* __restrict__ Dp, __hip_bfloat16* __restrict__ ycm)
{
    __shared__ __hip_bfloat16 ulds[L_];
    __shared__ __hip_bfloat16 st[CHK * 64];
    __shared__ float segT[8][32][2];
    int h = blockIdx.x >> 2, b = blockIdx.x & 3;
    int tid = threadIdx.x, w = tid >> 6, l = tid & 63, l15 = l & 15, l4 = l >> 4;
    const __hip_bfloat16* ub = ucm + (size_t)h * M_ + (size_t)b * L_;
    #pragma unroll
    for (int it = 0; it < 4; it++) {
        int e0 = it * 2048 + tid * 8;
        short8 v = *(const short8*)(ub + e0);
        int c = e0 >> 6, e = e0 & 63;
        *(short8*)&ulds[c * 64 + (e ^ ((c & 7) << 3))] = v;
    }
    __syncthreads();
    {
        const __hip_bfloat16* bbase = mw + (size_t)h * 4096 + l15 * 64 + l4 * 8;
        #pragma unroll
        for (int half = 0; half < 2; half++) {
            int g0 = (w + half * 4) * 16;
            int ca = g0 + l15;
            f32x4 acc[4];
            #pragma unroll
            for (int nj = 0; nj < 4; nj++) acc[nj] = (f32x4)0.f;
            #pragma unroll
            for (int ks = 0; ks < 2; ks++) {
                int e = l4 * 8 + ks * 32;
                bf16x8 a = *(const bf16x8*)&ulds[ca * 64 + (e ^ ((ca & 7) << 3))];
                #pragma unroll
                for (int nj = 0; nj < 4; nj++) {
                    bf16x8 bb = *(const bf16x8*)(bbase + nj * 16 * 64 + ks * 32);
                    acc[nj] = __builtin_amdgcn_mfma_f32_16x16x32_bf16(a, bb, acc[nj], 0, 0, 0);
                }
            }
            #pragma unroll
            for (int nj = 0; nj < 4; nj++)
                #pragma unroll
                for (int r = 0; r < 4; r++) {
                    int c = g0 + l4 * 4 + r, e = nj * 16 + l15;
                    st[c * 64 + (e ^ ((c & 7) << 3))] = __float2bfloat16(acc[nj][r]);
                }
        }
    }
    __syncthreads();
    {
        int s = tid >> 5, n = tid & 31;
        float2 wl = ((const float2*)(ws + OFF_PWLC))[(size_t)layer * H_ * N2_ + h * 32 + n];
        float tr = 0.f, ti = 0.f;
        for (int j = 0; j < 16; j++) {
            int c = s * 16 + j;
            __hip_bfloat162* p = (__hip_bfloat162*)&st[c * 64 + ((2 * n) ^ ((c & 7) << 3))];
            float2 v = __bfloat1622float2(*p);
            float nr = fmaf(wl.x, tr, v.x); nr = fmaf(-wl.y, ti, nr);
            float ni = fmaf(wl.x, ti, v.y); ni = fmaf(wl.y, tr, ni);
            tr = nr; ti = ni;
        }
        segT[s][n][0] = tr; segT[s][n][1] = ti;
        __syncthreads();
        float wr = wl.x, wi = wl.y;
        #pragma unroll
        for (int q = 0; q < 4; q++) {
            float nr = wr * wr - wi * wi, ni = 2.f * wr * wi;
            wr = nr; wi = ni;
        }
        float ar = 0.f, ai = 0.f;
        for (int t = 0; t < s; t++) {
            float Tx = segT[t][n][0], Ty = segT[t][n][1];
            float nr = fmaf(wr, ar, Tx); nr = fmaf(-wi, ai, nr);
            float ni = fmaf(wr, ai, Ty); ni = fmaf(wi, ar, ni);
            ar = nr; ai = ni;
        }
        for (int j = 0; j < 16; j++) {
            int c = s * 16 + j;
            __hip_bfloat162* p = (__hip_bfloat162*)&st[c * 64 + ((2 * n) ^ ((c & 7) << 3))];
            float2 v = __bfloat1622float2(*p);
            *p = __float22bfloat162_rn(make_float2(ar, ai));
            float nr = fmaf(wl.x, ar, v.x); nr = fmaf(-wl.y, ai, nr);
            float ni = fmaf(wl.x, ai, v.y); ni = fmaf(wl.y, ar, ni);
            ar = nr; ai = ni;
        }
    }
    __syncthreads();
    {
        const __hip_bfloat16* bt = mt + (size_t)h * 4096 + l15 * 64 + l4 * 8;
        const __hip_bfloat16* bv = mv + (size_t)h * 4096 + l15 * 64 + l4 * 8;
        float Dh = Dp[layer * H_ + h];
        __hip_bfloat16* yb = ycm + (size_t)h * M_ + (size_t)b * L_;
        #pragma unroll
        for (int half = 0; half < 2; half++) {
            int g0 = (w + half * 4) * 16;
            int ca = g0 + l15;
            f32x4 acc[4];
            #pragma unroll
            for (int nj = 0; nj < 4; nj++) acc[nj] = (f32x4)0.f;
            #pragma unroll
            for (int ks = 0; ks < 2; ks++) {
                int e = l4 * 8 + ks * 32;
                bf16x8 a = *(const bf16x8*)&ulds[ca * 64 + (e ^ ((ca & 7) << 3))];
                #pragma unroll
                for (int nj = 0; nj < 4; nj++) {
                    bf16x8 bb = *(const bf16x8*)(bt + nj * 16 * 64 + ks * 32);
                    acc[nj] = __builtin_amdgcn_mfma_f32_16x16x32_bf16(a, bb, acc[nj], 0, 0, 0);
                }
            }
            #pragma unroll
            for (int ks = 0; ks < 2; ks++) {
                int e = l4 * 8 + ks * 32;
                bf16x8 a = *(const bf16x8*)&st[ca * 64 + (e ^ ((ca & 7) << 3))];
                #pragma unroll
                for (int nj = 0; nj < 4; nj++) {
                    bf16x8 bb = *(const bf16x8*)(bv + nj * 16 * 64 + ks * 32);
                    acc[nj] = __builtin_amdgcn_mfma_f32_16x16x32_bf16(a, bb, acc[nj], 0, 0, 0);
                }
            }
            #pragma unroll
            for (int nj = 0; nj < 4; nj++)
                #pragma unroll
                for (int r = 0; r < 4; r++) {
                    int g = g0 + l4 * 4 + r;
                    int e = nj * 16 + l15;
                    float uv = __bfloat162float(ulds[g * 64 + (e ^ ((g & 7) << 3))]);
                    float v = fmaf(Dh, uv, acc[nj][r]);
                    float gg = 0.7978845608028654f * fmaf(0.044715f * v, v * v, v);
                    float yv = v / (1.f + __expf(-2.f * gg));
                    yb[(size_t)g * 64 + nj * 16 + l15] = __float2bfloat16(yv);
                }
        }
    }
}

// ---------------------------------------------------------------------------
// fused MFMA GLU+LN v13: grid 512, 512 threads (8 waves = 2 pos-tiles x 4 col
// quarters, parallel). Single LDS buffer: stage A -> K-loop -> restage R
// (from regs) -> GLU -> lt alias. u in-place.
__global__ __launch_bounds__(512) void k_glu_mfma(
    const __hip_bfloat16* __restrict__ ycm,  // [H][M] bf16 cm (A operand)
    const __hip_bfloat16* __restrict__ wob,  // [512,256] bf16
    const float* __restrict__ bo, const float* __restrict__ lnw,
    const float* __restrict__ lnb,
    __hip_bfloat16* __restrict__ u)          // [H][M] bf16 cm in/out (residual)
{
    __shared__ int buf[8704];                // [64 pos][130] dwords; lt alias
    __shared__ float red[2][4][32][2];
    int tid = threadIdx.x;
    int wt = tid >> 8;                       // pos-tile 0/1
    int t2 = tid & 255;
    int w = t2 >> 6, l = t2 & 63, l15 = l & 15, l4 = l >> 4;
    int mb = blockIdx.x * 64;
    int nv = w * 64;
    int p = tid & 127, q2 = tid >> 7;        // stage mapping: pair p, pos quarter q2

    // load A and R slices (2 ch x 16 pos each) into regs
    const __hip_bfloat16* aB = ycm + (size_t)(2 * p) * M_ + mb + q2 * 16;
    const __hip_bfloat16* rB = u + (size_t)(2 * p) * M_ + mb + q2 * 16;
    short8 A0a = *(const short8*)(aB);
    short8 A0b = *(const short8*)(aB + 8);
    short8 A1a = *(const short8*)(aB + M_);
    short8 A1b = *(const short8*)(aB + M_ + 8);
    short8 R0a = *(const short8*)(rB);
    short8 R0b = *(const short8*)(rB + 8);
    short8 R1a = *(const short8*)(rB + M_);
    short8 R1b = *(const short8*)(rB + M_ + 8);

    // LN/bias params
    float bov[4], bog[4], lw[4], lb[4];
    #pragma unroll
    for (int nj = 0; nj < 4; nj++) {
        int cn = nv + nj * 16 + l15;
        bov[nj] = bo[cn]; bog[nj] = bo[256 + cn];
        lw[nj] = lnw[cn]; lb[nj] = lnb[cn];
    }

    {   // stage A
        int* da = buf + q2 * 16 * 130 + p;
        #pragma unroll
        for (int j = 0; j < 8; j++) {
            da[j * 130]       = ((int)(unsigned short)A0a[j]) | (((int)(unsigned short)A1a[j]) << 16);
            da[(8 + j) * 130] = ((int)(unsigned short)A0b[j]) | (((int)(unsigned short)A1b[j]) << 16);
        }
    }
    __syncthreads();

    f32x4 accv[2][4], accg[2][4];
    #pragma unroll
    for (int sub = 0; sub < 2; sub++)
        #pragma unroll
        for (int nj = 0; nj < 4; nj++) { accv[sub][nj] = (f32x4)0.f; accg[sub][nj] = (f32x4)0.f; }

    int abase0 = (wt * 32 + l15) * 130 + l4 * 4;
    #pragma unroll 2
    for (int ks = 0; ks < 8; ks++) {
        int k0 = ks * 32 + l4 * 8;
        union { int2v d[2]; bf16x8 v; } a0u, a1u;
        a0u.d[0] = *(const int2v*)&buf[abase0 + ks * 16];
        a0u.d[1] = *(const int2v*)&buf[abase0 + ks * 16 + 2];
        a1u.d[0] = *(const int2v*)&buf[abase0 + 16 * 130 + ks * 16];
        a1u.d[1] = *(const int2v*)&buf[abase0 + 16 * 130 + ks * 16 + 2];
        bf16x8 a0 = a0u.v;
        bf16x8 a1 = a1u.v;
        #pragma unroll
        for (int nj = 0; nj < 4; nj++) {
            bf16x8 bv = *(const bf16x8*)(wob + (size_t)(nv + nj * 16 + l15) * H_ + k0);
            bf16x8 bg = *(const bf16x8*)(wob + (size_t)(256 + nv + nj * 16 + l15) * H_ + k0);
            accv[0][nj] = __builtin_amdgcn_mfma_f32_16x16x32_bf16(a0, bv, accv[0][nj], 0, 0, 0);
            accg[0][nj] = __builtin_amdgcn_mfma_f32_16x16x32_bf16(a0, bg, accg[0][nj], 0, 0, 0);
            accv[1][nj] = __builtin_amdgcn_mfma_f32_16x16x32_bf16(a1, bv, accv[1][nj], 0, 0, 0);
            accg[1][nj] = __builtin_amdgcn_mfma_f32_16x16x32_bf16(a1, bg, accg[1][nj], 0, 0, 0);
        }
    }
    __syncthreads();                        // A reads done

    {   // restage R into the same buffer
        int* dr = buf + q2 * 16 * 130 + p;
        #pragma unroll
        for (int j = 0; j < 8; j++) {
            dr[j * 130]       = ((int)(unsigned short)R0a[j]) | (((int)(unsigned short)R1a[j]) << 16);
            dr[(8 + j) * 130] = ((int)(unsigned short)R0b[j]) | (((int)(unsigned short)R1b[j]) << 16);
        }
    }
    __syncthreads();

    const short* bufRs = (const short*)buf;
    #pragma unroll
    for (int sub = 0; sub < 2; sub++) {
        #pragma unroll
        for (int r = 0; r < 4; r++) {
            int lr = sub * 16 + l4 * 4 + r;
            int gr = wt * 32 + lr;
            float s = 0.f, ss = 0.f;
            #pragma unroll
            for (int nj = 0; nj < 4; nj++) {
                int cn = nv + nj * 16 + l15;
                float uv = accv[sub][nj][r] + bov[nj];
                float ug = accg[sub][nj][r] + bog[nj];
                float z = uv / (1.f + __expf(-ug));
                float v = z + b2f(bufRs[gr * 260 + cn]);
                accv[sub][nj][r] = v;
                s += v; ss += v * v;
            }
            #pragma unroll
            for (int off = 1; off < 16; off <<= 1) {
                s  += __shfl_xor(s, off);
                ss += __shfl_xor(ss, off);
            }
            if (l15 == 0) { red[wt][w][lr][0] = s; red[wt][w][lr][1] = ss; }
        }
    }
    __syncthreads();                        // R reads done -> lt alias
    short* lt = (short*)buf;                // [256 ch][68] shorts
    #pragma unroll
    for (int sub = 0; sub < 2; sub++) {
        #pragma unroll
        for (int r = 0; r < 4; r++) {
            int lr = sub * 16 + l4 * 4 + r;
            int gr = wt * 32 + lr;
            float s  = red[wt][0][lr][0] + red[wt][1][lr][0] + red[wt][2][lr][0] + red[wt][3][lr][0];
            float ss = red[wt][0][lr][1] + red[wt][1][lr][1] + red[wt][2][lr][1] + red[wt][3][lr][1];
            float mu = s * (1.f / 256.f);
            float var = ss * (1.f / 256.f) - mu * mu;
            float rstd = rsqrtf(var + 1e-5f);
            #pragma unroll
            for (int nj = 0; nj < 4; nj++) {
                int cn = nv + nj * 16 + l15;
                float val = (accv[sub][nj][r] - mu) * rstd * lw[nj] + lb[nj];
                __hip_bfloat16 bval = __float2bfloat16(val);
                lt[cn * 68 + gr] = *(short*)&bval;
            }
        }
    }
    __syncthreads();
    {   // u write: thread = (channel tid>>1, 32-pos half tid&1)
        int ch = tid >> 1, hf = tid & 1;
        const short4v* lp = (const short4v*)(lt + ch * 68 + hf * 32);
        __hip_bfloat16* up = u + (size_t)ch * M_ + mb + hf * 32;
        #pragma unroll
        for (int q = 0; q < 4; q++) {
            alignas(16) short tmp8[8];
            *(short4v*)&tmp8[0] = lp[q * 2];
            *(short4v*)&tmp8[4] = lp[q * 2 + 1];
            *(short8*)(up + q * 8) = *(short8*)tmp8;
        }
    }
}

// ---------------------------------------------------------------------------
// decoder: stages u (cm) via pair-interleaved dword LDS (coalesced 64B rows)
__global__ __launch_bounds__(256) void k_decoder(const __hip_bfloat16* __restrict__ u,
    const float* __restrict__ out_W, const float* __restrict__ out_b,
    float* __restrict__ out)
{
    __shared__ int ds[64 * 130];             // [pos][130] pair-interleaved
    __shared__ float wl[10][260];
    int m0 = blockIdx.x * 64;
    int tid = threadIdx.x;
    {   // thread = (pair p, pos-half ph): 2 channels x 32 positions (64B rows)
        int p = tid & 127, ph = tid >> 7;
        const __hip_bfloat16* s0 = u + (size_t)(2 * p) * M_ + m0 + ph * 32;
        const __hip_bfloat16* s1 = s0 + M_;
        short8 y0[4], y1[4];
        #pragma unroll
        for (int q = 0; q < 4; q++) {
            y0[q] = *(const short8*)(s0 + q * 8);
            y1[q] = *(const short8*)(s1 + q * 8);
        }
        int* dst = ds + (ph * 32) * 130 + p;
        #pragma unroll
        for (int q = 0; q < 4; q++)
            #pragma unroll
            for (int j = 0; j < 8; j++)
                dst[(q * 8 + j) * 130] =
                    ((int)(unsigned short)y0[q][j]) | (((int)(unsigned short)y1[q][j]) << 16);
    }
    for (int q = tid; q < 640; q += 256) {
        int r = q / 64, k4 = q % 64;
        *(float4*)&wl[r][k4 * 4] = ((const float4*)out_W)[q];
    }
    __syncthreads();
    int slot = tid & 15;
    if (slot < DOUT) {
        #pragma unroll
        for (int pass = 0; pass < 4; pass++) {
            int pl = pass * 16 + (tid >> 4);
            const int* row = ds + pl * 130;
            float a0 = 0.f, a1 = 0.f;
            #pragma unroll 8
            for (int d = 0; d < 128; d++) {
                int v = row[d];
                a0 = fmaf(b2f((short)(v & 0xffff)),  wl[slot][2 * d],     a0);
                a1 = fmaf(b2f((short)(v >> 16)),     wl[slot][2 * d + 1], a1);
            }
            out[(size_t)(m0 + pl) * DOUT + slot] = a0 + a1 + out_b[slot];
        }
    }
}

// ---------------------------------------------------------------------------
extern "C" void kernel_launch(void* const* d_in, const int* in_sizes, int n_in,
                              void* d_out, int out_size, void* d_ws, size_t ws_size,
                              hipStream_t stream)
{
    (void)in_sizes; (void)n_in; (void)out_size; (void)ws_size;
    const float* x        = (const float*)d_in[0];
    const float* enc_W    = (const float*)d_in[1];
    const float* enc_b    = (const float*)d_in[2];
    const float* log_dt   = (const float*)d_in[3];
    const float* log_A_re = (const float*)d_in[4];
    const float* A_im     = (const float*)d_in[5];
    const float* C_re     = (const float*)d_in[6];
    const float* C_im     = (const float*)d_in[7];
    const float* Dp       = (const float*)d_in[8];
    const float* Wo       = (const float*)d_in[9];
    const float* bo       = (const float*)d_in[10];
    const float* lnw      = (const float*)d_in[11];
    const float* lnb      = (const float*)d_in[12];
    const float* out_W    = (const float*)d_in[13];
    const float* out_b    = (const float*)d_in[14];
    float* ws = (float*)d_ws;
    __hip_bfloat16* ewb = (__hip_bfloat16*)(ws + OFF_EWB);
    __hip_bfloat16* u   = (__hip_bfloat16*)(ws + OFF_UCM);
    __hip_bfloat16* ycm = (__hip_bfloat16*)(ws + OFF_YCM);
    __hip_bfloat16* mtA = (__hip_bfloat16*)(ws + OFF_MTA);
    __hip_bfloat16* mwA = (__hip_bfloat16*)(ws + OFF_MWA);
    __hip_bfloat16* mvA = (__hip_bfloat16*)(ws + OFF_MVA);
    __hip_bfloat16* wob = (__hip_bfloat16*)(ws + OFF_WOB);

    int n4a = NL_ * 2 * H_ * H_ / 4, n4b = H_ * DIN / 4;
    k_wcvt2<<<(n4a + n4b + 255) / 256, 256, 0, stream>>>(Wo, wob, n4a, enc_W, ewb, n4b);
    k_mats_all<<<NL_ * H_, 256, 0, stream>>>(log_dt, log_A_re, A_im, C_re, C_im,
                                             ws, mtA, mwA, mvA);
    k_encoder<<<M_ / 64, 256, 0, stream>>>(x, ewb, enc_b, u);
    for (int i = 0; i < NL_; i++) {
        k_ssm<<<H_ * B_, 256, 0, stream>>>(u,
            mtA + (size_t)i * H_ * 4096, mwA + (size_t)i * H_ * 4096,
            mvA + (size_t)i * H_ * 4096, ws, i, Dp, ycm);
        k_glu_mfma<<<M_ / 64, 512, 0, stream>>>(ycm,
            wob + (size_t)i * 2 * H_ * H_, bo + (size_t)i * 2 * H_,
            lnw + (size_t)i * H_, lnb + (size_t)i * H_, u);
    }
    k_decoder<<<M_ / 64, 256, 0, stream>>>(u, out_W, out_b, (float*)d_out);
}

// Round 20
// 359.728 us; speedup vs baseline: 1.0733x; 1.0733x over previous
//
#include <hip/hip_runtime.h>
#include <hip/hip_bf16.h>

// ---------------------------------------------------------------------------
// S4D stack, MFMA everywhere, single in-place state buffer u (bf16 [H][M]):
// prep: cvt(Wo+enc_W, 1 launch); mats_all (params inline, all layers).
// encoder MFMA (f32 x inline cvt -> u cm) -> 4x[ fused SSM; GLU MFMA + LN v12
//   (2-tile pipelined; u in-place) ] -> decoder (pair-interleaved staging).
// glu LDS: dword[pos][130]: dword p of row pos = short2(ch 2p, ch 2p+1)
// ---------------------------------------------------------------------------

constexpr int B_ = 4, L_ = 8192, DIN = 64, H_ = 256, N2_ = 32, NL_ = 4, DOUT = 10;
constexpr int LC = 64, CHK = L_ / LC;     // 128 chunks/batch
constexpr int M_ = B_ * L_;               // 32768 positions

// ws layout in float slots
constexpr size_t OFF_EWB  = 1048576;                   // bf16 enc_W [256*64]
constexpr size_t OFF_WOB  = 8388608;                   // bf16 Wo NL*512*256
constexpr size_t OFF_PWLC = 8781824;                   // f32 w^64 pairs (mats_all -> ssm)
constexpr size_t OFF_UCM  = 8929280;                   // bf16 [H][M] u (in-place)
constexpr size_t OFF_YCM  = 13123584;                  // bf16 [H][M] y cm
constexpr size_t OFF_MTA  = 17317888;                  // bf16 Ttr [NL][H][64][64]
constexpr size_t OFF_MWA  = 19415040;                  // bf16 Wtr [NL][H][64][64]
constexpr size_t OFF_MVA  = 21512192;                  // bf16 Vtr [NL][H][64][64]
// end 23609344 slots = 94.4 MB

typedef short bf16x8 __attribute__((ext_vector_type(8)));
typedef short short8 __attribute__((ext_vector_type(8)));
typedef short short4v __attribute__((ext_vector_type(4)));
typedef float f32x4  __attribute__((ext_vector_type(4)));
typedef int   int2v  __attribute__((ext_vector_type(2)));

__device__ __forceinline__ float b2f(short s) {
    union { float f; unsigned u; } c;
    c.u = ((unsigned)(unsigned short)s) << 16;
    return c.f;
}

// ---------------------------------------------------------------------------
// fused convert: Wo (n4a float4s) then enc_W (n4b float4s), one launch
__global__ __launch_bounds__(256) void k_wcvt2(const float* __restrict__ a,
    __hip_bfloat16* __restrict__ da, int n4a, const float* __restrict__ b,
    __hip_bfloat16* __restrict__ db, int n4b)
{
    int i = blockIdx.x * 256 + threadIdx.x;
    const float* s; __hip_bfloat16* d; int j;
    if (i < n4a) { s = a; d = da; j = i; }
    else if (i < n4a + n4b) { s = b; d = db; j = i - n4a; }
    else return;
    float4 v = ((const float4*)s)[j];
    union { __hip_bfloat16 bb[4]; uint2 u; } o;
    o.bb[0] = __float2bfloat16(v.x); o.bb[1] = __float2bfloat16(v.y);
    o.bb[2] = __float2bfloat16(v.z); o.bb[3] = __float2bfloat16(v.w);
    ((uint2*)d)[j] = o.u;
}

// ---------------------------------------------------------------------------
// ALL-LAYER mats with inline param computation; also writes PWLC for ssm.
__global__ __launch_bounds__(256) void k_mats_all(
    const float* __restrict__ log_dt, const float* __restrict__ log_A_re,
    const float* __restrict__ A_im, const float* __restrict__ C_re,
    const float* __restrict__ C_im, float* __restrict__ ws,
    __hip_bfloat16* __restrict__ mt, __hip_bfloat16* __restrict__ mw,
    __hip_bfloat16* __restrict__ mv)
{
    int lh = blockIdx.x;                   // NL*H blocks
    int tid = threadIdx.x;
    __shared__ float zre[32], zim[32], ctr[32], cti[32], kv[64];
    if (tid < 32) {
        int idx = lh * N2_ + tid;
        float dt  = expf(log_dt[lh]);
        float Are = -expf(log_A_re[idx]);
        float Aim = A_im[idx];
        float zr = dt * Are, zi = dt * Aim;
        float er = expf(zr);
        float wre = er * cosf(zi), wim = er * sinf(zi);
        float d = Are * Are + Aim * Aim;
        float nre = wre - 1.f, nim = wim;
        float qre = (nre * Are + nim * Aim) / d;
        float qim = (nim * Are - nre * Aim) / d;
        float cr = C_re[idx], ci = C_im[idx];
        zre[tid] = zr; zim[tid] = zi;
        ctr[tid] = 2.f * (cr * qre - ci * qim);
        cti[tid] = 2.f * (cr * qim + ci * qre);
        float er2 = expf(zr * (float)LC);
        ((float2*)(ws + OFF_PWLC))[idx] =
            make_float2(er2 * cosf(zi * (float)LC), er2 * sinf(zi * (float)LC));
    }
    __syncthreads();
    if (tid < 64) {
        float d = (float)tid, acc = 0.f;
        for (int n = 0; n < 32; n++) {
            float er = expf(zre[n] * d);
            float co = cosf(zim[n] * d), si = sinf(zim[n] * d);
            acc += er * (ctr[n] * co - cti[n] * si);
        }
        kv[tid] = acc;
    }
    __syncthreads();
    {   // Ttr
        int t = tid >> 2, j0 = (tid & 3) * 16;
        alignas(16) __hip_bfloat16 row[16];
        #pragma unroll
        for (int jj = 0; jj < 16; jj++) {
            int j = j0 + jj;
            row[jj] = __float2bfloat16(j <= t ? kv[t - j] : 0.f);
        }
        *(short8*)(mt + (size_t)lh*4096 + t*64 + j0)     = *(short8*)&row[0];
        *(short8*)(mt + (size_t)lh*4096 + t*64 + j0 + 8) = *(short8*)&row[8];
    }
    {   // Wtr
        int n = tid >> 3, j0 = (tid & 7) * 8;
        alignas(16) __hip_bfloat16 rre[8], rim[8];
        #pragma unroll
        for (int jj = 0; jj < 8; jj++) {
            float e = (float)(63 - (j0 + jj));
            float er = expf(zre[n] * e);
            rre[jj] = __float2bfloat16(er * cosf(zim[n] * e));
            rim[jj] = __float2bfloat16(er * sinf(zim[n] * e));
        }
        *(short8*)(mw + (size_t)lh*4096 + (2*n)*64 + j0)   = *(short8*)&rre[0];
        *(short8*)(mw + (size_t)lh*4096 + (2*n+1)*64 + j0) = *(short8*)&rim[0];
    }
    {   // Vtr
        int t = tid >> 2, n0 = (tid & 3) * 8;
        float e = (float)(t + 1);
        alignas(16) __hip_bfloat16 row[16];
        #pragma unroll
        for (int k = 0; k < 8; k++) {
            int n = n0 + k;
            float er = expf(zre[n] * e);
            float wr = er * cosf(zim[n] * e), wi = er * sinf(zim[n] * e);
            row[2*k]   = __float2bfloat16(ctr[n]*wr - cti[n]*wi);
            row[2*k+1] = __float2bfloat16(-(ctr[n]*wi + cti[n]*wr));
        }
        *(short8*)(mv + (size_t)lh*4096 + t*64 + 2*n0)     = *(short8*)&row[0];
        *(short8*)(mv + (size_t)lh*4096 + t*64 + 2*n0 + 8) = *(short8*)&row[8];
    }
}

// ---------------------------------------------------------------------------
// encoder MFMA: u[cm] = (x @ ewb^T + b); x f32 converted inline via LDS
__global__ __launch_bounds__(256) void k_encoder(const float* __restrict__ x,
    const __hip_bfloat16* __restrict__ ewb, const float* __restrict__ enc_b,
    __hip_bfloat16* __restrict__ u)
{
    __shared__ short sbuf[256 * 66];        // xls [64][72] alias; lt
    short* xls = sbuf;
    int tid = threadIdx.x;
    int w = tid >> 6, l = tid & 63, l15 = l & 15, l4 = l >> 4;
    int m0 = blockIdx.x * 64;
    int nv = w * 64;
    {   // stage x f32 -> bf16 LDS [row][72]
        const float4* x4 = (const float4*)x;
        #pragma unroll
        for (int q = 0; q < 4; q++) {
            int f = tid * 4 + q;
            float4 v = x4[(size_t)m0 * 16 + f];
            int e = f * 4, row = e >> 6, col = e & 63;
            alignas(8) __hip_bfloat16 t4[4] = {
                __float2bfloat16(v.x), __float2bfloat16(v.y),
                __float2bfloat16(v.z), __float2bfloat16(v.w) };
            *(short4v*)&xls[row * 72 + col] = *(short4v*)t4;
        }
    }
    __syncthreads();
    f32x4 acc[4][4];
    #pragma unroll
    for (int mi = 0; mi < 4; mi++)
        #pragma unroll
        for (int nj = 0; nj < 4; nj++) acc[mi][nj] = (f32x4)0.f;
    #pragma unroll
    for (int ks = 0; ks < 2; ks++) {
        int k0 = ks * 32 + l4 * 8;
        bf16x8 a[4];
        #pragma unroll
        for (int mi = 0; mi < 4; mi++)
            a[mi] = *(const bf16x8*)&xls[(mi * 16 + l15) * 72 + k0];
        #pragma unroll
        for (int nj = 0; nj < 4; nj++) {
            bf16x8 b = *(const bf16x8*)(ewb + (size_t)(nv + nj * 16 + l15) * 64 + k0);
            #pragma unroll
            for (int mi = 0; mi < 4; mi++)
                acc[mi][nj] = __builtin_amdgcn_mfma_f32_16x16x32_bf16(a[mi], b, acc[mi][nj], 0, 0, 0);
        }
    }
    float bov[4];
    #pragma unroll
    for (int nj = 0; nj < 4; nj++) bov[nj] = enc_b[nv + nj * 16 + l15];
    __syncthreads();                        // xls dead -> lt
    #pragma unroll
    for (int mi = 0; mi < 4; mi++)
        #pragma unroll
        for (int r = 0; r < 4; r++) {
            int lr = mi * 16 + l4 * 4 + r;
            #pragma unroll
            for (int nj = 0; nj < 4; nj++) {
                int cn = nv + nj * 16 + l15;
                __hip_bfloat16 bv = __float2bfloat16(acc[mi][nj][r] + bov[nj]);
                sbuf[cn * 66 + lr] = *(short*)&bv;
            }
        }
    __syncthreads();
    #pragma unroll
    for (int q = 0; q < 8; q++)
        *(short8*)(u + (size_t)tid * M_ + m0 + q * 8) = *(short8*)&sbuf[tid * 66 + q * 8];
}

// ---------------------------------------------------------------------------
// FUSED SSM (unchanged)
__global__ __launch_bounds__(256) void k_ssm(const __hip_bfloat16* __restrict__ ucm,
    const __hip_bfloat16* __restrict__ mt, const __hip_bfloat16* __restrict__ mw,
    const __hip_bfloat16* __restrict__ mv, const float* __restrict__ ws, int layer,
    const float* __restrict__ Dp, __hip_bfloat16* __restrict__ ycm)
{
    __shared__ __hip_bfloat16 ulds[L_];
    __shared__ __hip_bfloat16 st[CHK * 64];
    __shared__ float segT[8][32][2];
    int h = blockIdx.x >> 2, b = blockIdx.x & 3;
    int tid = threadIdx.x, w = tid >> 6, l = tid & 63, l15 = l & 15, l4 = l >> 4;
    const __hip_bfloat16* ub = ucm + (size_t)h * M_ + (size_t)b * L_;
    #pragma unroll
    for (int it = 0; it < 4; it++) {
        int e0 = it * 2048 + tid * 8;
        short8 v = *(const short8*)(ub + e0);
        int c = e0 >> 6, e = e0 & 63;
        *(short8*)&ulds[c * 64 + (e ^ ((c & 7) << 3))] = v;
    }
    __syncthreads();
    {
        const __hip_bfloat16* bbase = mw + (size_t)h * 4096 + l15 * 64 + l4 * 8;
        #pragma unroll
        for (int half = 0; half < 2; half++) {
            int g0 = (w + half * 4) * 16;
            int ca = g0 + l15;
            f32x4 acc[4];
            #pragma unroll
            for (int nj = 0; nj < 4; nj++) acc[nj] = (f32x4)0.f;
            #pragma unroll
            for (int ks = 0; ks < 2; ks++) {
                int e = l4 * 8 + ks * 32;
                bf16x8 a = *(const bf16x8*)&ulds[ca * 64 + (e ^ ((ca & 7) << 3))];
                #pragma unroll
                for (int nj = 0; nj < 4; nj++) {
                    bf16x8 bb = *(const bf16x8*)(bbase + nj * 16 * 64 + ks * 32);
                    acc[nj] = __builtin_amdgcn_mfma_f32_16x16x32_bf16(a, bb, acc[nj], 0, 0, 0);
                }
            }
            #pragma unroll
            for (int nj = 0; nj < 4; nj++)
                #pragma unroll
                for (int r = 0; r < 4; r++) {
                    int c = g0 + l4 * 4 + r, e = nj * 16 + l15;
                    st[c * 64 + (e ^ ((c & 7) << 3))] = __float2bfloat16(acc[nj][r]);
                }
        }
    }
    __syncthreads();
    {
        int s = tid >> 5, n = tid & 31;
        float2 wl = ((const float2*)(ws + OFF_PWLC))[(size_t)layer * H_ * N2_ + h * 32 + n];
        float tr = 0.f, ti = 0.f;
        for (int j = 0; j < 16; j++) {
            int c = s * 16 + j;
            __hip_bfloat162* p = (__hip_bfloat162*)&st[c * 64 + ((2 * n) ^ ((c & 7) << 3))];
            float2 v = __bfloat1622float2(*p);
            float nr = fmaf(wl.x, tr, v.x); nr = fmaf(-wl.y, ti, nr);
            float ni = fmaf(wl.x, ti, v.y); ni = fmaf(wl.y, tr, ni);
            tr = nr; ti = ni;
        }
        segT[s][n][0] = tr; segT[s][n][1] = ti;
        __syncthreads();
        float wr = wl.x, wi = wl.y;
        #pragma unroll
        for (int q = 0; q < 4; q++) {
            float nr = wr * wr - wi * wi, ni = 2.f * wr * wi;
            wr = nr; wi = ni;
        }
        float ar = 0.f, ai = 0.f;
        for (int t = 0; t < s; t++) {
            float Tx = segT[t][n][0], Ty = segT[t][n][1];
            float nr = fmaf(wr, ar, Tx); nr = fmaf(-wi, ai, nr);
            float ni = fmaf(wr, ai, Ty); ni = fmaf(wi, ar, ni);
            ar = nr; ai = ni;
        }
        for (int j = 0; j < 16; j++) {
            int c = s * 16 + j;
            __hip_bfloat162* p = (__hip_bfloat162*)&st[c * 64 + ((2 * n) ^ ((c & 7) << 3))];
            float2 v = __bfloat1622float2(*p);
            *p = __float22bfloat162_rn(make_float2(ar, ai));
            float nr = fmaf(wl.x, ar, v.x); nr = fmaf(-wl.y, ai, nr);
            float ni = fmaf(wl.x, ai, v.y); ni = fmaf(wl.y, ar, ni);
            ar = nr; ai = ni;
        }
    }
    __syncthreads();
    {
        const __hip_bfloat16* bt = mt + (size_t)h * 4096 + l15 * 64 + l4 * 8;
        const __hip_bfloat16* bv = mv + (size_t)h * 4096 + l15 * 64 + l4 * 8;
        float Dh = Dp[layer * H_ + h];
        __hip_bfloat16* yb = ycm + (size_t)h * M_ + (size_t)b * L_;
        #pragma unroll
        for (int half = 0; half < 2; half++) {
            int g0 = (w + half * 4) * 16;
            int ca = g0 + l15;
            f32x4 acc[4];
            #pragma unroll
            for (int nj = 0; nj < 4; nj++) acc[nj] = (f32x4)0.f;
            #pragma unroll
            for (int ks = 0; ks < 2; ks++) {
                int e = l4 * 8 + ks * 32;
                bf16x8 a = *(const bf16x8*)&ulds[ca * 64 + (e ^ ((ca & 7) << 3))];
                #pragma unroll
                for (int nj = 0; nj < 4; nj++) {
                    bf16x8 bb = *(const bf16x8*)(bt + nj * 16 * 64 + ks * 32);
                    acc[nj] = __builtin_amdgcn_mfma_f32_16x16x32_bf16(a, bb, acc[nj], 0, 0, 0);
                }
            }
            #pragma unroll
            for (int ks = 0; ks < 2; ks++) {
                int e = l4 * 8 + ks * 32;
                bf16x8 a = *(const bf16x8*)&st[ca * 64 + (e ^ ((ca & 7) << 3))];
                #pragma unroll
                for (int nj = 0; nj < 4; nj++) {
                    bf16x8 bb = *(const bf16x8*)(bv + nj * 16 * 64 + ks * 32);
                    acc[nj] = __builtin_amdgcn_mfma_f32_16x16x32_bf16(a, bb, acc[nj], 0, 0, 0);
                }
            }
            #pragma unroll
            for (int nj = 0; nj < 4; nj++)
                #pragma unroll
                for (int r = 0; r < 4; r++) {
                    int g = g0 + l4 * 4 + r;
                    int e = nj * 16 + l15;
                    float uv = __bfloat162float(ulds[g * 64 + (e ^ ((g & 7) << 3))]);
                    float v = fmaf(Dh, uv, acc[nj][r]);
                    float gg = 0.7978845608028654f * fmaf(0.044715f * v, v * v, v);
                    float yv = v / (1.f + __expf(-2.f * gg));
                    yb[(size_t)g * 64 + nj * 16 + l15] = __float2bfloat16(yv);
                }
        }
    }
}

// ---------------------------------------------------------------------------
// fused MFMA GLU+LN v12 (r18 best): grid 512, 2 pipelined 32-pos tiles/block.
__global__ __launch_bounds__(256) void k_glu_mfma(
    const __hip_bfloat16* __restrict__ ycm,  // [H][M] bf16 cm (A operand)
    const __hip_bfloat16* __restrict__ wob,  // [512,256] bf16
    const float* __restrict__ bo, const float* __restrict__ lnw,
    const float* __restrict__ lnb,
    __hip_bfloat16* __restrict__ u)          // [H][M] bf16 cm in/out (residual)
{
    __shared__ int buf[8320];                // bufA[4160] + bufR[4160]; lt alias
    __shared__ float red[4][32][2];
    int* bufA = buf;
    int* bufR = buf + 4160;
    int tid = threadIdx.x;
    int w = tid >> 6, l = tid & 63, l15 = l & 15, l4 = l >> 4;
    int mb = blockIdx.x * 64;
    int nv = w * 64;
    int p = tid & 127, ph = tid >> 7;
    const __hip_bfloat16* aB = ycm + (size_t)(2 * p) * M_ + mb + ph * 16;
    const __hip_bfloat16* rB = u + (size_t)(2 * p) * M_ + mb + ph * 16;

    short8 A0[4], R0[4], A1[4], R1[4];
    A0[0] = *(const short8*)(aB);          A0[1] = *(const short8*)(aB + 8);
    A0[2] = *(const short8*)(aB + M_);     A0[3] = *(const short8*)(aB + M_ + 8);
    R0[0] = *(const short8*)(rB);          R0[1] = *(const short8*)(rB + 8);
    R0[2] = *(const short8*)(rB + M_);     R0[3] = *(const short8*)(rB + M_ + 8);
    A1[0] = *(const short8*)(aB + 32);     A1[1] = *(const short8*)(aB + 40);
    A1[2] = *(const short8*)(aB + M_ + 32);A1[3] = *(const short8*)(aB + M_ + 40);

    float bov[4], bog[4], lw[4], lb[4];
    #pragma unroll
    for (int nj = 0; nj < 4; nj++) {
        int cn = nv + nj * 16 + l15;
        bov[nj] = bo[cn]; bog[nj] = bo[256 + cn];
        lw[nj] = lnw[cn]; lb[nj] = lnb[cn];
    }

    {
        int* da = bufA + ph * 16 * 130 + p;
        int* dr = bufR + ph * 16 * 130 + p;
        #pragma unroll
        for (int j = 0; j < 8; j++) {
            da[j * 130]       = ((int)(unsigned short)A0[0][j]) | (((int)(unsigned short)A0[2][j]) << 16);
            da[(8 + j) * 130] = ((int)(unsigned short)A0[1][j]) | (((int)(unsigned short)A0[3][j]) << 16);
            dr[j * 130]       = ((int)(unsigned short)R0[0][j]) | (((int)(unsigned short)R0[2][j]) << 16);
            dr[(8 + j) * 130] = ((int)(unsigned short)R0[1][j]) | (((int)(unsigned short)R0[3][j]) << 16);
        }
    }
    __syncthreads();

    int abase0 = l15 * 130 + l4 * 4;
    #pragma unroll
    for (int tile = 0; tile < 2; tile++) {
        int m0 = mb + tile * 32;
        f32x4 accv[2][4], accg[2][4];
        #pragma unroll
        for (int sub = 0; sub < 2; sub++)
            #pragma unroll
            for (int nj = 0; nj < 4; nj++) { accv[sub][nj] = (f32x4)0.f; accg[sub][nj] = (f32x4)0.f; }

        #pragma unroll 2
        for (int ks = 0; ks < 8; ks++) {
            int k0 = ks * 32 + l4 * 8;
            union { int2v d[2]; bf16x8 v; } a0u, a1u;
            a0u.d[0] = *(const int2v*)&bufA[abase0 + ks * 16];
            a0u.d[1] = *(const int2v*)&bufA[abase0 + ks * 16 + 2];
            a1u.d[0] = *(const int2v*)&bufA[abase0 + 16 * 130 + ks * 16];
            a1u.d[1] = *(const int2v*)&bufA[abase0 + 16 * 130 + ks * 16 + 2];
            bf16x8 a0 = a0u.v;
            bf16x8 a1 = a1u.v;
            #pragma unroll
            for (int nj = 0; nj < 4; nj++) {
                bf16x8 bv = *(const bf16x8*)(wob + (size_t)(nv + nj * 16 + l15) * H_ + k0);
                bf16x8 bg = *(const bf16x8*)(wob + (size_t)(256 + nv + nj * 16 + l15) * H_ + k0);
                accv[0][nj] = __builtin_amdgcn_mfma_f32_16x16x32_bf16(a0, bv, accv[0][nj], 0, 0, 0);
                accg[0][nj] = __builtin_amdgcn_mfma_f32_16x16x32_bf16(a0, bg, accg[0][nj], 0, 0, 0);
                accv[1][nj] = __builtin_amdgcn_mfma_f32_16x16x32_bf16(a1, bv, accv[1][nj], 0, 0, 0);
                accg[1][nj] = __builtin_amdgcn_mfma_f32_16x16x32_bf16(a1, bg, accg[1][nj], 0, 0, 0);
            }
        }

        const short* bufRs = (const short*)bufR;
        #pragma unroll
        for (int sub = 0; sub < 2; sub++) {
            #pragma unroll
            for (int r = 0; r < 4; r++) {
                int lr = sub * 16 + l4 * 4 + r;
                float s = 0.f, ss = 0.f;
                #pragma unroll
                for (int nj = 0; nj < 4; nj++) {
                    int cn = nv + nj * 16 + l15;
                    float uv = accv[sub][nj][r] + bov[nj];
                    float ug = accg[sub][nj][r] + bog[nj];
                    float z = uv / (1.f + __expf(-ug));
                    float v = z + b2f(bufRs[lr * 260 + cn]);
                    accv[sub][nj][r] = v;
                    s += v; ss += v * v;
                }
                #pragma unroll
                for (int off = 1; off < 16; off <<= 1) {
                    s  += __shfl_xor(s, off);
                    ss += __shfl_xor(ss, off);
                }
                if (l15 == 0) { red[w][lr][0] = s; red[w][lr][1] = ss; }
            }
        }
        if (tile == 0) {
            R1[0] = *(const short8*)(rB + 32);      R1[1] = *(const short8*)(rB + 40);
            R1[2] = *(const short8*)(rB + M_ + 32); R1[3] = *(const short8*)(rB + M_ + 40);
        }
        __syncthreads();
        short* lt = (short*)buf;
        #pragma unroll
        for (int sub = 0; sub < 2; sub++) {
            #pragma unroll
            for (int r = 0; r < 4; r++) {
                int lr = sub * 16 + l4 * 4 + r;
                float s  = red[0][lr][0] + red[1][lr][0] + red[2][lr][0] + red[3][lr][0];
                float ss = red[0][lr][1] + red[1][lr][1] + red[2][lr][1] + red[3][lr][1];
                float mu = s * (1.f / 256.f);
                float var = ss * (1.f / 256.f) - mu * mu;
                float rstd = rsqrtf(var + 1e-5f);
                #pragma unroll
                for (int nj = 0; nj < 4; nj++) {
                    int cn = nv + nj * 16 + l15;
                    float val = (accv[sub][nj][r] - mu) * rstd * lw[nj] + lb[nj];
                    __hip_bfloat16 bval = __float2bfloat16(val);
                    lt[cn * 34 + lr] = *(short*)&bval;
                }
            }
        }
        __syncthreads();
        #pragma unroll
        for (int q = 0; q < 4; q++)
            *(short8*)(u + (size_t)tid * M_ + m0 + q * 8)
                = *(short8*)&lt[tid * 34 + q * 8];
        if (tile == 0) {
            __syncthreads();
            int* da = bufA + ph * 16 * 130 + p;
            int* dr = bufR + ph * 16 * 130 + p;
            #pragma unroll
            for (int j = 0; j < 8; j++) {
                da[j * 130]       = ((int)(unsigned short)A1[0][j]) | (((int)(unsigned short)A1[2][j]) << 16);
                da[(8 + j) * 130] = ((int)(unsigned short)A1[1][j]) | (((int)(unsigned short)A1[3][j]) << 16);
                dr[j * 130]       = ((int)(unsigned short)R1[0][j]) | (((int)(unsigned short)R1[2][j]) << 16);
                dr[(8 + j) * 130] = ((int)(unsigned short)R1[1][j]) | (((int)(unsigned short)R1[3][j]) << 16);
            }
            __syncthreads();
        }
    }
}

// ---------------------------------------------------------------------------
// decoder: stages u (cm) via pair-interleaved dword LDS (coalesced 64B rows)
__global__ __launch_bounds__(256) void k_decoder(const __hip_bfloat16* __restrict__ u,
    const float* __restrict__ out_W, const float* __restrict__ out_b,
    float* __restrict__ out)
{
    __shared__ int ds[64 * 130];             // [pos][130] pair-interleaved
    __shared__ float wl[10][260];
    int m0 = blockIdx.x * 64;
    int tid = threadIdx.x;
    {   // thread = (pair p, pos-half ph): 2 channels x 32 positions (64B rows)
        int p = tid & 127, ph = tid >> 7;
        const __hip_bfloat16* s0 = u + (size_t)(2 * p) * M_ + m0 + ph * 32;
        const __hip_bfloat16* s1 = s0 + M_;
        short8 y0[4], y1[4];
        #pragma unroll
        for (int q = 0; q < 4; q++) {
            y0[q] = *(const short8*)(s0 + q * 8);
            y1[q] = *(const short8*)(s1 + q * 8);
        }
        int* dst = ds + (ph * 32) * 130 + p;
        #pragma unroll
        for (int q = 0; q < 4; q++)
            #pragma unroll
            for (int j = 0; j < 8; j++)
                dst[(q * 8 + j) * 130] =
                    ((int)(unsigned short)y0[q][j]) | (((int)(unsigned short)y1[q][j]) << 16);
    }
    for (int q = tid; q < 640; q += 256) {
        int r = q / 64, k4 = q % 64;
        *(float4*)&wl[r][k4 * 4] = ((const float4*)out_W)[q];
    }
    __syncthreads();
    int slot = tid & 15;
    if (slot < DOUT) {
        #pragma unroll
        for (int pass = 0; pass < 4; pass++) {
            int pl = pass * 16 + (tid >> 4);
            const int* row = ds + pl * 130;
            float a0 = 0.f, a1 = 0.f;
            #pragma unroll 8
            for (int d = 0; d < 128; d++) {
                int v = row[d];
                a0 = fmaf(b2f((short)(v & 0xffff)),  wl[slot][2 * d],     a0);
                a1 = fmaf(b2f((short)(v >> 16)),     wl[slot][2 * d + 1], a1);
            }
            out[(size_t)(m0 + pl) * DOUT + slot] = a0 + a1 + out_b[slot];
        }
    }
}

// ---------------------------------------------------------------------------
extern "C" void kernel_launch(void* const* d_in, const int* in_sizes, int n_in,
                              void* d_out, int out_size, void* d_ws, size_t ws_size,
                              hipStream_t stream)
{
    (void)in_sizes; (void)n_in; (void)out_size; (void)ws_size;
    const float* x        = (const float*)d_in[0];
    const float* enc_W    = (const float*)d_in[1];
    const float* enc_b    = (const float*)d_in[2];
    const float* log_dt   = (const float*)d_in[3];
    const float* log_A_re = (const float*)d_in[4];
    const float* A_im     = (const float*)d_in[5];
    const float* C_re     = (const float*)d_in[6];
    const float* C_im     = (const float*)d_in[7];
    const float* Dp       = (const float*)d_in[8];
    const float* Wo       = (const float*)d_in[9];
    const float* bo       = (const float*)d_in[10];
    const float* lnw      = (const float*)d_in[11];
    const float* lnb      = (const float*)d_in[12];
    const float* out_W    = (const float*)d_in[13];
    const float* out_b    = (const float*)d_in[14];
    float* ws = (float*)d_ws;
    __hip_bfloat16* ewb = (__hip_bfloat16*)(ws + OFF_EWB);
    __hip_bfloat16* u   = (__hip_bfloat16*)(ws + OFF_UCM);
    __hip_bfloat16* ycm = (__hip_bfloat16*)(ws + OFF_YCM);
    __hip_bfloat16* mtA = (__hip_bfloat16*)(ws + OFF_MTA);
    __hip_bfloat16* mwA = (__hip_bfloat16*)(ws + OFF_MWA);
    __hip_bfloat16* mvA = (__hip_bfloat16*)(ws + OFF_MVA);
    __hip_bfloat16* wob = (__hip_bfloat16*)(ws + OFF_WOB);

    int n4a = NL_ * 2 * H_ * H_ / 4, n4b = H_ * DIN / 4;
    k_wcvt2<<<(n4a + n4b + 255) / 256, 256, 0, stream>>>(Wo, wob, n4a, enc_W, ewb, n4b);
    k_mats_all<<<NL_ * H_, 256, 0, stream>>>(log_dt, log_A_re, A_im, C_re, C_im,
                                             ws, mtA, mwA, mvA);
    k_encoder<<<M_ / 64, 256, 0, stream>>>(x, ewb, enc_b, u);
    for (int i = 0; i < NL_; i++) {
        k_ssm<<<H_ * B_, 256, 0, stream>>>(u,
            mtA + (size_t)i * H_ * 4096, mwA + (size_t)i * H_ * 4096,
            mvA + (size_t)i * H_ * 4096, ws, i, Dp, ycm);
        k_glu_mfma<<<M_ / 64, 256, 0, stream>>>(ycm,
            wob + (size_t)i * 2 * H_ * H_, bo + (size_t)i * 2 * H_,
            lnw + (size_t)i * H_, lnb + (size_t)i * H_, u);
    }
    k_decoder<<<M_ / 64, 256, 0, stream>>>(u, out_W, out_b, (float*)d_out);
}